// Round 19
// baseline (2310.111 us; speedup 1.0000x reference)
//
#include <hip/hip_runtime.h>
#include <math.h>

#define N    257     // state dim
#define AP   258     // floats per A row (cols 0..256 = S, col 257 = rhs)
#define MM   128     // rotation pairs
#define LL   512     // seq length
#define BB   4       // batch
#define NB   32      // panel width
#define U12S 226     // U12 row stride

// ws byte layout (round-14 verified, fp32 LU):
#define A_BYTE    0         // float[257*258] = 265224
#define W0_BYTE   265224    // float[257]  -> 266252
#define CXY_BYTE  266256    // float[4096] -> 282640
#define PW_BYTE   282640    // float[32*257] = 32896 -> 315536
#define U12_BYTE  315536    // float[32*226] = 28928 -> 344464
#define ST_BYTE   344464    // float[257*257] = 264196 -> 608660
// total ~609 KB (ws >= 1.31 MB)

// ---------------------------------------------------------------------------
// stage + scan in ONE dispatch (r14 verified).
// ---------------------------------------------------------------------------
__global__ __launch_bounds__(512) void stage_scan_kernel(const float* __restrict__ S,
                                                         const float* __restrict__ z0,
                                                         const float* __restrict__ x,
                                                         void* __restrict__ wsv) {
  const int tid = threadIdx.x;
  const int bid = blockIdx.x;

  if (bid < 130) {
    float* A  = (float*)((char*)wsv + A_BYTE);
    float* St = (float*)((char*)wsv + ST_BYTE);
    const int idx = bid * 512 + tid;
    if (idx < N * N) {
      const int i = idx / N, j = idx - i * N;
      A[(size_t)i * AP + j] = S[idx];
      St[idx] = S[j * N + i];          // St[d][i] = S[i][d]
    } else if (idx < N * N + N) {
      const int r = idx - N * N;
      A[(size_t)r * AP + N] = z0[r];
    }
    return;
  }

  const int wave = tid >> 6, lane = tid & 63;
  const int b    = wave >> 1, comp = wave & 1;
  const float* xp = x + ((size_t)b * LL) * 2 + comp;
  double loc[8];
  double run = 0.0;
  #pragma unroll
  for (int e = 0; e < 8; ++e) {
    run += (double)xp[(lane * 8 + e) * 2];
    loc[e] = run;
  }
  double tot = run;
  #pragma unroll
  for (int off = 1; off < 64; off <<= 1) {
    const double o = __shfl_up(tot, off);
    if (lane >= off) tot += o;
  }
  const double excl = tot - run;
  float* cp = (float*)((char*)wsv + CXY_BYTE) + ((size_t)b * LL) * 2 + comp;
  #pragma unroll
  for (int e = 0; e < 8; ++e)
    cp[(lane * 8 + e) * 2] = (float)(excl + loc[e]);
}

// ---------------------------------------------------------------------------
// panel factor (round-19): SINGLE-WAVE all-shfl Jordan, compile-time K0.
// r16/r17 evidence: the 320-thr structure costs ~650cy/step (barrier across
// 5 waves + LDS pinv/piv round-trip + publisher tail); neither issue-width
// (r16) nor phase-halving (r17) moved it. This kernel removes barriers and
// per-step LDS entirely: 64 threads (1 wave), thread t owns rows t+64s
// (s=0..4, r[5][32]=160 VGPR @ 1 wave -> within budget, no 512-thread
// 128-cap), pivot row broadcast via __shfl from owner lane L=(K0+j)&63,
// slot S=(K0+j)>>6 -- BOTH compile-time via template<K0>, so all register
// indexing is static (r8/r12/r13 spill causes designed out). Frozen rows
// via branchless per-lane predication (f=0).
// Bit-exactness vs r16: d is the same pivot value; pinv=1/d identical IEEE
// in every lane; per-element update order and U12 chain order unchanged.
// absmax must be EXACTLY 1.625. Tripwires: VGPR<=100 => spill => revert;
// factor >=20us => revert.
// ---------------------------------------------------------------------------
template<int K0>
__global__ __launch_bounds__(64, 1) void panel_factor_kernel(void* __restrict__ wsv) {
  __shared__ __align__(16) float F11s[NB][NB + 4]; // 144B rows, 16B aligned
  float* A    = (float*)((char*)wsv + A_BYTE);
  float* Pw   = (float*)((char*)wsv + PW_BYTE);
  float* U12w = (float*)((char*)wsv + U12_BYTE);
  const int t = threadIdx.x;
  constexpr int CT  = K0 + NB;
  constexpr int TC2 = 258 - CT;          // trailing cols incl rhs

  // ---- stage: thread t owns rows t+64s, s=0..4 ----
  float r[5][NB];
  #pragma unroll
  for (int s = 0; s < 5; ++s) {
    const int gr = t + 64 * s;
    if (gr < N) {
      const float* Ar = A + (size_t)gr * AP + K0;   // 8B-aligned (K0 even)
      #pragma unroll
      for (int c = 0; c < NB; c += 2) {
        const float2 v = *(const float2*)&Ar[c];
        r[s][c] = v.x; r[s][c + 1] = v.y;
      }
    } else {
      #pragma unroll
      for (int c = 0; c < NB; ++c) r[s][c] = 0.0f;  // inert (f=0 forever)
    }
  }

  // ---- 32 Jordan steps, zero barriers, pivot row via shfl ----
  #pragma unroll
  for (int j = 0; j < NB; ++j) {
    const int g = K0 + j;                 // compile-time
    const int L = g & 63;                 // compile-time lane
    const int S = g >> 6;                 // compile-time slot
    const float d    = __shfl(r[S][j], L);
    const float pinv = 1.0f / d;          // identical IEEE result in all lanes
    float pe[NB];
    #pragma unroll
    for (int c = j + 1; c < NB; ++c)
      pe[c] = __shfl(r[S][c], L);         // pivot row trailing elements
    #pragma unroll
    for (int s = 0; s < 5; ++s) {
      const int gr = t + 64 * s;
      const bool active = (gr < K0) || (gr > g);   // frozen: pivot rows K0..g
      const float f = active ? r[s][j] * pinv : 0.0f;
      #pragma unroll
      for (int c = j + 1; c < NB; ++c)
        r[s][c] -= f * pe[c];             // f=0 -> no-op for frozen/inert rows
      if (active) r[s][j] = f;
    }
  }

  // ---- publish: band rows -> F11s + A; other rows -> Pw ----
  #pragma unroll
  for (int s = 0; s < 5; ++s) {
    const int gr = t + 64 * s;
    if (gr < N) {
      if (gr >= K0 && gr < CT) {
        const int fr = gr - K0;
        #pragma unroll
        for (int c = 0; c < NB; ++c) {
          F11s[fr][c] = r[s][c];
          A[(size_t)gr * AP + K0 + c] = r[s][c];   // U11/L11 for finish kernel
        }
      } else {
        #pragma unroll
        for (int tt = 0; tt < NB; ++tt)
          Pw[(size_t)tt * N + gr] = r[s][tt];
      }
    }
  }
  __syncthreads();                                  // F11s visible

  // ---- U12 forward solve: thread t owns cols t+64s (s=0..3), u in regs ----
  float u[4][NB];
  #pragma unroll
  for (int s = 0; s < 4; ++s) {
    const int col = t + 64 * s;
    if (col < TC2) {
      #pragma unroll
      for (int jr = 0; jr < NB; ++jr)
        u[s][jr] = A[(size_t)(K0 + jr) * AP + CT + col];   // coalesced
    } else {
      #pragma unroll
      for (int jr = 0; jr < NB; ++jr) u[s][jr] = 0.0f;
    }
  }
  #pragma unroll
  for (int jr = 1; jr < NB; ++jr) {
    float vv0 = u[0][jr], vv1 = u[1][jr], vv2 = u[2][jr], vv3 = u[3][jr];
    #pragma unroll
    for (int q = 0; q < jr / 4; ++q) {
      const float4 fv = *(const float4*)&F11s[jr][4 * q];
      // per-column op order identical to r16 (sequential fma chain)
      vv0 -= fv.x * u[0][4 * q]; vv0 -= fv.y * u[0][4 * q + 1];
      vv0 -= fv.z * u[0][4 * q + 2]; vv0 -= fv.w * u[0][4 * q + 3];
      vv1 -= fv.x * u[1][4 * q]; vv1 -= fv.y * u[1][4 * q + 1];
      vv1 -= fv.z * u[1][4 * q + 2]; vv1 -= fv.w * u[1][4 * q + 3];
      vv2 -= fv.x * u[2][4 * q]; vv2 -= fv.y * u[2][4 * q + 1];
      vv2 -= fv.z * u[2][4 * q + 2]; vv2 -= fv.w * u[2][4 * q + 3];
      vv3 -= fv.x * u[3][4 * q]; vv3 -= fv.y * u[3][4 * q + 1];
      vv3 -= fv.z * u[3][4 * q + 2]; vv3 -= fv.w * u[3][4 * q + 3];
    }
    #pragma unroll
    for (int tt = (jr / 4) * 4; tt < jr; ++tt) {
      const float fs = F11s[jr][tt];
      vv0 -= fs * u[0][tt]; vv1 -= fs * u[1][tt];
      vv2 -= fs * u[2][tt]; vv3 -= fs * u[3][tt];
    }
    u[0][jr] = vv0; u[1][jr] = vv1; u[2][jr] = vv2; u[3][jr] = vv3;
  }
  #pragma unroll
  for (int s = 0; s < 4; ++s) {
    const int col = t + 64 * s;
    if (col < TC2) {
      #pragma unroll
      for (int jr = 0; jr < NB; ++jr) {
        U12w[jr * U12S + col] = u[s][jr];
        A[(size_t)(K0 + jr) * AP + CT + col] = u[s][jr];
      }
    }
  }
}

// ---------------------------------------------------------------------------
// panel update (rank-32 Jordan GEMM), r14-verified fp32 body (p = 0..6).
// ---------------------------------------------------------------------------
__global__ __launch_bounds__(256) void panel_update_kernel(void* __restrict__ wsv,
                                                           int k0, int tc2) {
  __shared__ float Pl[NB][NB + 1];
  __shared__ __align__(16) float Ul[NB][66];
  float* A = (float*)((char*)wsv + A_BYTE);
  const float* Pw   = (const float*)((const char*)wsv + PW_BYTE);
  const float* U12w = (const float*)((const char*)wsv + U12_BYTE);
  const int tid = threadIdx.x;
  const int ct  = k0 + NB;
  const int rb0 = blockIdx.x * 32;
  const int c0  = blockIdx.y * 64;

  for (int i = tid; i < 32 * 32; i += 256) {
    const int t = i >> 5, rr = i & 31;
    const int rb = rb0 + rr;
    const int gr = (rb < k0) ? rb : rb + NB;
    Pl[t][rr] = (rb < 225) ? Pw[(size_t)t * N + gr] : 0.0f;
  }
  for (int i = tid; i < 32 * 64; i += 256) {
    const int t = i >> 6, c = i & 63;
    Ul[t][c] = (c0 + c < tc2) ? U12w[t * U12S + c0 + c] : 0.0f;
  }
  __syncthreads();

  const int tr  = tid >> 4;          // 0..15 -> rows tr*2 .. +1
  const int tcx = (tid & 15) * 4;    // cols tcx .. +3
  float acc[2][4];
  #pragma unroll
  for (int rr = 0; rr < 2; ++rr) {
    const int rb = rb0 + tr * 2 + rr;
    const int gr = (rb < k0) ? rb : rb + NB;
    #pragma unroll
    for (int c = 0; c < 4; ++c)
      acc[rr][c] = (rb < 225 && (c0 + tcx + c) < tc2)
                 ? A[(size_t)gr * AP + ct + c0 + tcx + c] : 0.0f;
  }
  #pragma unroll
  for (int t = 0; t < NB; ++t) {
    const float p0 = Pl[t][tr * 2], p1 = Pl[t][tr * 2 + 1];
    const float2 u0 = *(const float2*)&Ul[t][tcx];
    const float2 u1 = *(const float2*)&Ul[t][tcx + 2];
    acc[0][0] -= p0 * u0.x; acc[0][1] -= p0 * u0.y;
    acc[0][2] -= p0 * u1.x; acc[0][3] -= p0 * u1.y;
    acc[1][0] -= p1 * u0.x; acc[1][1] -= p1 * u0.y;
    acc[1][2] -= p1 * u1.x; acc[1][3] -= p1 * u1.y;
  }
  #pragma unroll
  for (int rr = 0; rr < 2; ++rr) {
    const int rb = rb0 + tr * 2 + rr;
    const int gr = (rb < k0) ? rb : rb + NB;
    #pragma unroll
    for (int c = 0; c < 4; ++c)
      if (rb < 225 && (c0 + tcx + c) < tc2)
        A[(size_t)gr * AP + ct + c0 + tcx + c] = acc[rr][c];
  }
}

// ---------------------------------------------------------------------------
// last: update(p=7) (225 rows x 2 cols, rank-32) + finish back-substs
// (r14-verified fp32 body).
// ---------------------------------------------------------------------------
__global__ __launch_bounds__(256) void last_kernel(void* __restrict__ wsv) {
  __shared__ float xs[N];
  __shared__ float rr[256];
  float* A = (float*)((char*)wsv + A_BYTE);
  const float* Pw   = (const float*)((const char*)wsv + PW_BYTE);
  const float* U12w = (const float*)((const char*)wsv + U12_BYTE);
  float* w0f = (float*)((char*)wsv + W0_BYTE);
  const int tid = threadIdx.x;

  // update(7): rows [0,224) U {256}, cols {256, 257}
  for (int idx = tid; idx < 225 * 2; idx += 256) {
    const int rb = idx >> 1, c = idx & 1;
    const int gr = (rb < 224) ? rb : 256;
    float acc = A[(size_t)gr * AP + 256 + c];
    #pragma unroll
    for (int t = 0; t < NB; ++t)
      acc -= Pw[(size_t)t * N + gr] * U12w[t * U12S + c];
    A[(size_t)gr * AP + 256 + c] = acc;
  }
  __threadfence_block();
  __syncthreads();

  // finish (r6-verified body, fp32)
  if (tid == 0) xs[256] = A[256 * AP + 257] / A[256 * AP + 256];
  __syncthreads();
  const float x256 = xs[256];
  rr[tid] = A[(size_t)tid * AP + 257] - A[(size_t)tid * AP + 256] * x256;
  __syncthreads();
  const int fk0 = tid & ~31;
  const int fs  = tid & 31;
  for (int j = 31; j >= 0; --j) {
    if (fs == j) xs[fk0 + j] = rr[fk0 + j] / A[(size_t)(fk0 + j) * AP + (fk0 + j)];
    __syncthreads();
    if (fs < j) rr[fk0 + fs] -= A[(size_t)(fk0 + fs) * AP + (fk0 + j)] * xs[fk0 + j];
    __syncthreads();
  }
  w0f[tid] = xs[tid];
  if (tid == 0) w0f[256] = xs[256];
}

// ---------------------------------------------------------------------------
// combine: out[(b,l), i] = sum_d St[d, i] * W[(b,l), d]   (round-4 verified)
// ---------------------------------------------------------------------------
#define NL 8
__global__ __launch_bounds__(320) void combine_kernel(const float* __restrict__ S,
                                                      const float* __restrict__ om,
                                                      const void* __restrict__ wsv,
                                                      float* __restrict__ out) {
  const int tid = threadIdx.x;
  const int b  = blockIdx.y;
  const int l0 = blockIdx.x * NL;
  const float* w0  = (const float*)((const char*)wsv + W0_BYTE);
  const float* cxy = (const float*)((const char*)wsv + CXY_BYTE);
  const float* St  = (const float*)((const char*)wsv + ST_BYTE);
  __shared__ __align__(16) float Wl[N][NL];
  __shared__ float omsh[2 * MM];
  __shared__ float cxs[NL], cys[NL];

  for (int idx = tid; idx < 2 * MM; idx += 320) omsh[idx] = om[idx];
  if (tid < NL) {
    cxs[tid] = cxy[((size_t)(b * LL) + l0 + tid) * 2];
    cys[tid] = cxy[((size_t)(b * LL) + l0 + tid) * 2 + 1];
  }
  __syncthreads();

  for (int idx = tid; idx < NL * N; idx += 320) {
    const int d = idx >> 3;
    const int r = idx & 7;
    float v;
    if (d == 0) {
      v = w0[0];
    } else {
      const int m = (d - 1) >> 1;
      const int pq = 2 * m + 1;
      const float t = cxs[r] * omsh[2 * m] + cys[r] * omsh[2 * m + 1];
      float s, c;
      sincosf(t, &s, &c);
      const float a0 = w0[pq], a1 = w0[pq + 1];
      v = (d & 1) ? (c * a0 - s * a1) : (s * a0 + c * a1);
    }
    Wl[d][r] = v;
  }
  __syncthreads();

  const int i = tid;
  if (i < N) {
    float acc[NL];
    #pragma unroll
    for (int r = 0; r < NL; ++r) acc[r] = 0.0f;
    #pragma unroll 8
    for (int d = 0; d < N; ++d) {
      const float stv = St[(size_t)d * N + i];
      const float4 wa = *(const float4*)&Wl[d][0];
      const float4 wb = *(const float4*)&Wl[d][4];
      acc[0] += stv * wa.x; acc[1] += stv * wa.y;
      acc[2] += stv * wa.z; acc[3] += stv * wa.w;
      acc[4] += stv * wb.x; acc[5] += stv * wb.y;
      acc[6] += stv * wb.z; acc[7] += stv * wb.w;
    }
    const size_t base = (size_t)(b * LL + l0) * N + i;
    #pragma unroll
    for (int r = 0; r < NL; ++r) out[base + (size_t)r * N] = acc[r];
    if (l0 + NL == LL) {
      out[(size_t)BB * LL * N + (size_t)b * N + i] = acc[NL - 1];
    }
  }
}

extern "C" void kernel_launch(void* const* d_in, const int* in_sizes, int n_in,
                              void* d_out, int out_size, void* d_ws, size_t ws_size,
                              hipStream_t stream) {
  const float* x  = (const float*)d_in[0];   // (B, L, 2)
  const float* z0 = (const float*)d_in[1];   // (D,)
  const float* om = (const float*)d_in[2];   // (M, 2)
  const float* S  = (const float*)d_in[3];   // (D, D)
  float* out = (float*)d_out;                // outputs (B,L,D) then z_final (B,D)

  hipLaunchKernelGGL(stage_scan_kernel, dim3(131), dim3(512), 0, stream, S, z0, x, d_ws);
  for (int p = 0; p < 8; ++p) {
    const int k0  = p * NB;
    const int tc2 = 258 - (k0 + NB);
    switch (p) {   // template<K0> -> compile-time pivot lane/slot indices
      case 0: hipLaunchKernelGGL(panel_factor_kernel<0 * NB>, dim3(1), dim3(64), 0, stream, d_ws); break;
      case 1: hipLaunchKernelGGL(panel_factor_kernel<1 * NB>, dim3(1), dim3(64), 0, stream, d_ws); break;
      case 2: hipLaunchKernelGGL(panel_factor_kernel<2 * NB>, dim3(1), dim3(64), 0, stream, d_ws); break;
      case 3: hipLaunchKernelGGL(panel_factor_kernel<3 * NB>, dim3(1), dim3(64), 0, stream, d_ws); break;
      case 4: hipLaunchKernelGGL(panel_factor_kernel<4 * NB>, dim3(1), dim3(64), 0, stream, d_ws); break;
      case 5: hipLaunchKernelGGL(panel_factor_kernel<5 * NB>, dim3(1), dim3(64), 0, stream, d_ws); break;
      case 6: hipLaunchKernelGGL(panel_factor_kernel<6 * NB>, dim3(1), dim3(64), 0, stream, d_ws); break;
      case 7: hipLaunchKernelGGL(panel_factor_kernel<7 * NB>, dim3(1), dim3(64), 0, stream, d_ws); break;
    }
    if (p < 7)
      hipLaunchKernelGGL(panel_update_kernel, dim3(8, (tc2 + 63) / 64), dim3(256),
                         0, stream, d_ws, k0, tc2);
  }
  hipLaunchKernelGGL(last_kernel, dim3(1), dim3(256), 0, stream, d_ws);
  hipLaunchKernelGGL(combine_kernel, dim3(LL / NL, BB), dim3(320), 0, stream, S, om, d_ws, out);
}

// Round 20
// 295.015 us; speedup vs baseline: 7.8305x; 7.8305x over previous
//
#include <hip/hip_runtime.h>
#include <math.h>

#define N    257     // state dim
#define AP   258     // floats per A row (cols 0..256 = S, col 257 = rhs)
#define MM   128     // rotation pairs
#define LL   512     // seq length
#define BB   4       // batch
#define NB   32      // panel width
#define U12S 226     // U12 row stride

// ws byte layout (round-14 verified, fp32 LU):
#define A_BYTE    0         // float[257*258] = 265224
#define W0_BYTE   265224    // float[257]  -> 266252
#define CXY_BYTE  266256    // float[4096] -> 282640
#define PW_BYTE   282640    // float[32*257] = 32896 -> 315536
#define U12_BYTE  315536    // float[32*226] = 28928 -> 344464
#define ST_BYTE   344464    // float[257*257] = 264196 -> 608660
// total ~609 KB (ws >= 1.31 MB)

// ---------------------------------------------------------------------------
// stage + scan in ONE dispatch (r14 verified).
// ---------------------------------------------------------------------------
__global__ __launch_bounds__(512) void stage_scan_kernel(const float* __restrict__ S,
                                                         const float* __restrict__ z0,
                                                         const float* __restrict__ x,
                                                         void* __restrict__ wsv) {
  const int tid = threadIdx.x;
  const int bid = blockIdx.x;

  if (bid < 130) {
    float* A  = (float*)((char*)wsv + A_BYTE);
    float* St = (float*)((char*)wsv + ST_BYTE);
    const int idx = bid * 512 + tid;
    if (idx < N * N) {
      const int i = idx / N, j = idx - i * N;
      A[(size_t)i * AP + j] = S[idx];
      St[idx] = S[j * N + i];          // St[d][i] = S[i][d]
    } else if (idx < N * N + N) {
      const int r = idx - N * N;
      A[(size_t)r * AP + N] = z0[r];
    }
    return;
  }

  const int wave = tid >> 6, lane = tid & 63;
  const int b    = wave >> 1, comp = wave & 1;
  const float* xp = x + ((size_t)b * LL) * 2 + comp;
  double loc[8];
  double run = 0.0;
  #pragma unroll
  for (int e = 0; e < 8; ++e) {
    run += (double)xp[(lane * 8 + e) * 2];
    loc[e] = run;
  }
  double tot = run;
  #pragma unroll
  for (int off = 1; off < 64; off <<= 1) {
    const double o = __shfl_up(tot, off);
    if (lane >= off) tot += o;
  }
  const double excl = tot - run;
  float* cp = (float*)((char*)wsv + CXY_BYTE) + ((size_t)b * LL) * 2 + comp;
  #pragma unroll
  for (int e = 0; e < 8; ++e)
    cp[(lane * 8 + e) * 2] = (float)(excl + loc[e]);
}

// ---------------------------------------------------------------------------
// panel factor (r16 verified): fp32 register-resident Jordan; float4 applied
// to LOADS ONLY, operation order bit-identical to r14 (absmax 1.625 margin).
// Factor-structure history: r12 vec-LDS (spill), r13 hybrid-shfl (spill),
// r15 reassoc (absmax fail), r16 float4-loads (pass, -0.5us), r17 2-step
// phases (+3us/factor), r19 single-wave shfl (VGPR cap 256, scratch, 16x).
// Law: at most ONE ~32-elem register array per kernel; uniform role context;
// scalar LDS stores. ~650cy/step = the measured floor for this structure.
// ---------------------------------------------------------------------------
__global__ __launch_bounds__(320, 1) void panel_factor_kernel(void* __restrict__ wsv,
                                                              int k0) {
  __shared__ __align__(16) float piv[2][NB];       // 128B rows, 16B aligned
  __shared__ float pinvs[2];
  __shared__ __align__(16) float F11s[NB][NB + 4]; // 144B rows, 16B aligned
  float* A    = (float*)((char*)wsv + A_BYTE);
  float* Pw   = (float*)((char*)wsv + PW_BYTE);
  float* U12w = (float*)((char*)wsv + U12_BYTE);
  const int tid = threadIdx.x;
  const int ct  = k0 + NB;
  const int tc2 = 258 - ct;              // trailing cols incl rhs

  // ---- stage my row's panel slice into registers (L2-resident A) ----
  float r[NB];
  if (tid < N) {
    const float* Ar = A + (size_t)tid * AP + k0;
    #pragma unroll
    for (int c = 0; c < NB; c += 2) {
      const float2 v = *(const float2*)&Ar[c];
      r[c] = v.x; r[c + 1] = v.y;
    }
  }

  // ---- pre-step: pivot row k0 publishes itself (scalar stores) ----
  if (tid == k0) {
    #pragma unroll
    for (int c = 0; c < NB; ++c) piv[0][c] = r[c];
    pinvs[0] = 1.0f / r[0];
  }
  __syncthreads();

  // ---- 32 Jordan steps; pivot row via FLOAT4 LDS broadcast,
  //      per-element updates (bit-identical to r14) ----
  #pragma unroll
  for (int j = 0; j < NB; ++j) {
    const int pr = k0 + j;
    const int bsel = j & 1;
    if (tid < N && (tid < k0 || tid > pr)) {   // frozen: pivot rows k0..pr
      const float f = r[j] * pinvs[bsel];
      #pragma unroll
      for (int q = 0; q < NB / 4; ++q) {
        if (4 * q + 3 > j) {                   // quad has a live column
          const float4 pv = *(const float4*)&piv[bsel][4 * q];
          if (4 * q     > j) r[4 * q]     -= f * pv.x;   // compile-time guards
          if (4 * q + 1 > j) r[4 * q + 1] -= f * pv.y;
          if (4 * q + 2 > j) r[4 * q + 2] -= f * pv.z;
          r[4 * q + 3] -= f * pv.w;            // 4q+3 > j by outer guard
        }
      }
      r[j] = f;
      if (j + 1 < NB && tid == pr + 1) {       // publish next pivot row (scalar)
        #pragma unroll
        for (int c = 0; c < NB; ++c)
          if (c > j) piv[bsel ^ 1][c] = r[c];
        pinvs[bsel ^ 1] = 1.0f / r[j + 1];
      }
    }
    __syncthreads();
  }

  // ---- publish: pivot band -> F11s + A; other rows -> Pw (scalar) ----
  if (tid < N) {
    if (tid >= k0 && tid < ct) {
      const int fr = tid - k0;
      #pragma unroll
      for (int c = 0; c < NB; ++c) {
        F11s[fr][c] = r[c];
        A[(size_t)tid * AP + k0 + c] = r[c];   // U11/L11 for finish kernel
      }
    } else {
      #pragma unroll
      for (int t = 0; t < NB; ++t)
        Pw[(size_t)t * N + tid] = r[t];
    }
  }
  __syncthreads();                             // F11s ready

  // ---- U12 forward solve: float4 F11s reads, SEQUENTIAL fma chain
  //      (r14's exact operation order -> bit-identical) ----
  if (tid < tc2) {
    float u[NB];
    #pragma unroll
    for (int jr = 0; jr < NB; ++jr)
      u[jr] = A[(size_t)(k0 + jr) * AP + ct + tid];   // coalesced across tid
    #pragma unroll
    for (int jr = 1; jr < NB; ++jr) {
      float vv = u[jr];
      #pragma unroll
      for (int q = 0; q < jr / 4; ++q) {
        const float4 fv = *(const float4*)&F11s[jr][4 * q];
        vv -= fv.x * u[4 * q];                 // sequential, same order as r14
        vv -= fv.y * u[4 * q + 1];
        vv -= fv.z * u[4 * q + 2];
        vv -= fv.w * u[4 * q + 3];
      }
      #pragma unroll
      for (int t = (jr / 4) * 4; t < jr; ++t)
        vv -= F11s[jr][t] * u[t];              // remainder, scalar
      u[jr] = vv;
    }
    #pragma unroll
    for (int jr = 0; jr < NB; ++jr) {
      U12w[jr * U12S + tid] = u[jr];
      A[(size_t)(k0 + jr) * AP + ct + tid] = u[jr];
    }
  }
}

// ---------------------------------------------------------------------------
// panel update (rank-32 Jordan GEMM), r14-verified fp32 body (p = 0..6).
// ---------------------------------------------------------------------------
__global__ __launch_bounds__(256) void panel_update_kernel(void* __restrict__ wsv,
                                                           int k0, int tc2) {
  __shared__ float Pl[NB][NB + 1];
  __shared__ __align__(16) float Ul[NB][66];
  float* A = (float*)((char*)wsv + A_BYTE);
  const float* Pw   = (const float*)((const char*)wsv + PW_BYTE);
  const float* U12w = (const float*)((const char*)wsv + U12_BYTE);
  const int tid = threadIdx.x;
  const int ct  = k0 + NB;
  const int rb0 = blockIdx.x * 32;
  const int c0  = blockIdx.y * 64;

  for (int i = tid; i < 32 * 32; i += 256) {
    const int t = i >> 5, rr = i & 31;
    const int rb = rb0 + rr;
    const int gr = (rb < k0) ? rb : rb + NB;
    Pl[t][rr] = (rb < 225) ? Pw[(size_t)t * N + gr] : 0.0f;
  }
  for (int i = tid; i < 32 * 64; i += 256) {
    const int t = i >> 6, c = i & 63;
    Ul[t][c] = (c0 + c < tc2) ? U12w[t * U12S + c0 + c] : 0.0f;
  }
  __syncthreads();

  const int tr  = tid >> 4;          // 0..15 -> rows tr*2 .. +1
  const int tcx = (tid & 15) * 4;    // cols tcx .. +3
  float acc[2][4];
  #pragma unroll
  for (int rr = 0; rr < 2; ++rr) {
    const int rb = rb0 + tr * 2 + rr;
    const int gr = (rb < k0) ? rb : rb + NB;
    #pragma unroll
    for (int c = 0; c < 4; ++c)
      acc[rr][c] = (rb < 225 && (c0 + tcx + c) < tc2)
                 ? A[(size_t)gr * AP + ct + c0 + tcx + c] : 0.0f;
  }
  #pragma unroll
  for (int t = 0; t < NB; ++t) {
    const float p0 = Pl[t][tr * 2], p1 = Pl[t][tr * 2 + 1];
    const float2 u0 = *(const float2*)&Ul[t][tcx];
    const float2 u1 = *(const float2*)&Ul[t][tcx + 2];
    acc[0][0] -= p0 * u0.x; acc[0][1] -= p0 * u0.y;
    acc[0][2] -= p0 * u1.x; acc[0][3] -= p0 * u1.y;
    acc[1][0] -= p1 * u0.x; acc[1][1] -= p1 * u0.y;
    acc[1][2] -= p1 * u1.x; acc[1][3] -= p1 * u1.y;
  }
  #pragma unroll
  for (int rr = 0; rr < 2; ++rr) {
    const int rb = rb0 + tr * 2 + rr;
    const int gr = (rb < k0) ? rb : rb + NB;
    #pragma unroll
    for (int c = 0; c < 4; ++c)
      if (rb < 225 && (c0 + tcx + c) < tc2)
        A[(size_t)gr * AP + ct + c0 + tcx + c] = acc[rr][c];
  }
}

// ---------------------------------------------------------------------------
// last: update(p=7) (225 rows x 2 cols, rank-32) + finish back-substs
// (r14-verified fp32 body).
// ---------------------------------------------------------------------------
__global__ __launch_bounds__(256) void last_kernel(void* __restrict__ wsv) {
  __shared__ float xs[N];
  __shared__ float rr[256];
  float* A = (float*)((char*)wsv + A_BYTE);
  const float* Pw   = (const float*)((const char*)wsv + PW_BYTE);
  const float* U12w = (const float*)((const char*)wsv + U12_BYTE);
  float* w0f = (float*)((char*)wsv + W0_BYTE);
  const int tid = threadIdx.x;

  // update(7): rows [0,224) U {256}, cols {256, 257}
  for (int idx = tid; idx < 225 * 2; idx += 256) {
    const int rb = idx >> 1, c = idx & 1;
    const int gr = (rb < 224) ? rb : 256;
    float acc = A[(size_t)gr * AP + 256 + c];
    #pragma unroll
    for (int t = 0; t < NB; ++t)
      acc -= Pw[(size_t)t * N + gr] * U12w[t * U12S + c];
    A[(size_t)gr * AP + 256 + c] = acc;
  }
  __threadfence_block();
  __syncthreads();

  // finish (r6-verified body, fp32)
  if (tid == 0) xs[256] = A[256 * AP + 257] / A[256 * AP + 256];
  __syncthreads();
  const float x256 = xs[256];
  rr[tid] = A[(size_t)tid * AP + 257] - A[(size_t)tid * AP + 256] * x256;
  __syncthreads();
  const int fk0 = tid & ~31;
  const int fs  = tid & 31;
  for (int j = 31; j >= 0; --j) {
    if (fs == j) xs[fk0 + j] = rr[fk0 + j] / A[(size_t)(fk0 + j) * AP + (fk0 + j)];
    __syncthreads();
    if (fs < j) rr[fk0 + fs] -= A[(size_t)(fk0 + fs) * AP + (fk0 + j)] * xs[fk0 + j];
    __syncthreads();
  }
  w0f[tid] = xs[tid];
  if (tid == 0) w0f[256] = xs[256];
}

// ---------------------------------------------------------------------------
// combine: out[(b,l), i] = sum_d St[d, i] * W[(b,l), d]   (round-4 verified)
// ---------------------------------------------------------------------------
#define NL 8
__global__ __launch_bounds__(320) void combine_kernel(const float* __restrict__ S,
                                                      const float* __restrict__ om,
                                                      const void* __restrict__ wsv,
                                                      float* __restrict__ out) {
  const int tid = threadIdx.x;
  const int b  = blockIdx.y;
  const int l0 = blockIdx.x * NL;
  const float* w0  = (const float*)((const char*)wsv + W0_BYTE);
  const float* cxy = (const float*)((const char*)wsv + CXY_BYTE);
  const float* St  = (const float*)((const char*)wsv + ST_BYTE);
  __shared__ __align__(16) float Wl[N][NL];
  __shared__ float omsh[2 * MM];
  __shared__ float cxs[NL], cys[NL];

  for (int idx = tid; idx < 2 * MM; idx += 320) omsh[idx] = om[idx];
  if (tid < NL) {
    cxs[tid] = cxy[((size_t)(b * LL) + l0 + tid) * 2];
    cys[tid] = cxy[((size_t)(b * LL) + l0 + tid) * 2 + 1];
  }
  __syncthreads();

  for (int idx = tid; idx < NL * N; idx += 320) {
    const int d = idx >> 3;
    const int r = idx & 7;
    float v;
    if (d == 0) {
      v = w0[0];
    } else {
      const int m = (d - 1) >> 1;
      const int pq = 2 * m + 1;
      const float t = cxs[r] * omsh[2 * m] + cys[r] * omsh[2 * m + 1];
      float s, c;
      sincosf(t, &s, &c);
      const float a0 = w0[pq], a1 = w0[pq + 1];
      v = (d & 1) ? (c * a0 - s * a1) : (s * a0 + c * a1);
    }
    Wl[d][r] = v;
  }
  __syncthreads();

  const int i = tid;
  if (i < N) {
    float acc[NL];
    #pragma unroll
    for (int r = 0; r < NL; ++r) acc[r] = 0.0f;
    #pragma unroll 8
    for (int d = 0; d < N; ++d) {
      const float stv = St[(size_t)d * N + i];
      const float4 wa = *(const float4*)&Wl[d][0];
      const float4 wb = *(const float4*)&Wl[d][4];
      acc[0] += stv * wa.x; acc[1] += stv * wa.y;
      acc[2] += stv * wa.z; acc[3] += stv * wa.w;
      acc[4] += stv * wb.x; acc[5] += stv * wb.y;
      acc[6] += stv * wb.z; acc[7] += stv * wb.w;
    }
    const size_t base = (size_t)(b * LL + l0) * N + i;
    #pragma unroll
    for (int r = 0; r < NL; ++r) out[base + (size_t)r * N] = acc[r];
    if (l0 + NL == LL) {
      out[(size_t)BB * LL * N + (size_t)b * N + i] = acc[NL - 1];
    }
  }
}

extern "C" void kernel_launch(void* const* d_in, const int* in_sizes, int n_in,
                              void* d_out, int out_size, void* d_ws, size_t ws_size,
                              hipStream_t stream) {
  const float* x  = (const float*)d_in[0];   // (B, L, 2)
  const float* z0 = (const float*)d_in[1];   // (D,)
  const float* om = (const float*)d_in[2];   // (M, 2)
  const float* S  = (const float*)d_in[3];   // (D, D)
  float* out = (float*)d_out;                // outputs (B,L,D) then z_final (B,D)

  hipLaunchKernelGGL(stage_scan_kernel, dim3(131), dim3(512), 0, stream, S, z0, x, d_ws);
  for (int p = 0; p < 8; ++p) {
    const int k0  = p * NB;
    const int tc2 = 258 - (k0 + NB);
    hipLaunchKernelGGL(panel_factor_kernel, dim3(1), dim3(320), 0, stream, d_ws, k0);
    if (p < 7)
      hipLaunchKernelGGL(panel_update_kernel, dim3(8, (tc2 + 63) / 64), dim3(256),
                         0, stream, d_ws, k0, tc2);
  }
  hipLaunchKernelGGL(last_kernel, dim3(1), dim3(256), 0, stream, d_ws);
  hipLaunchKernelGGL(combine_kernel, dim3(LL / NL, BB), dim3(320), 0, stream, S, om, d_ws, out);
}